// Round 1
// baseline (465.992 us; speedup 1.0000x reference)
//
#include <hip/hip_runtime.h>
#include <hip/hip_bf16.h>

#define NH 12
#define HD 64
#define NB 4
#define SEQ 2048
#define NP 768
#define ATT_SCALE 0.125f

typedef __bf16 bf16x8 __attribute__((ext_vector_type(8)));
typedef float f32x4 __attribute__((ext_vector_type(4)));

static __device__ __forceinline__ bf16x8 load_bf16x8(const __bf16* p) {
    return *reinterpret_cast<const bf16x8*>(p);
}

// ---------------------------------------------------------------------------
// Kernel 1: QKV projection. hidden (B*T,64) fp32 @ W (64,768) fp32 + bias.
// One 16(t)x16(p) tile per wave, K=64 via two 16x16x32 bf16 MFMAs.
// Q,K written bf16 as (B*H, T, 64); V written TRANSPOSED as (B*H, 64, T).
// Block = 4 waves stacked along t (64 rows) so V^T stores from one block
// cover full cache lines along t.
// ---------------------------------------------------------------------------
__global__ __launch_bounds__(256) void qkv_proj_kernel(
    const float* __restrict__ hidden,
    const float* __restrict__ Wq, const float* __restrict__ bq,
    const float* __restrict__ Wk, const float* __restrict__ bk,
    const float* __restrict__ Wv, const float* __restrict__ bv,
    __bf16* __restrict__ Qw, __bf16* __restrict__ Kw, __bf16* __restrict__ Vtw)
{
    const int lane = threadIdx.x & 63;
    const int w    = threadIdx.x >> 6;
    const int g    = lane >> 4;    // quad
    const int n    = lane & 15;
    const int pi   = blockIdx.z;

    const float* W;
    const float* bias;
    if (pi == 0)      { W = Wq; bias = bq; }
    else if (pi == 1) { W = Wk; bias = bk; }
    else              { W = Wv; bias = bv; }

    const int pbase = blockIdx.y * 16;          // 0..752
    const int bt0   = blockIdx.x * 64 + w * 16; // wave's first (b,t) row

    // A fragment: A[m=lane&15][k=quad*8+j], two frags cover K=64
    const float* hrow = hidden + (size_t)(bt0 + n) * HD + 8 * g;
    f32x4 h0 = *(const f32x4*)(hrow);
    f32x4 h1 = *(const f32x4*)(hrow + 4);
    f32x4 h2 = *(const f32x4*)(hrow + 32);
    f32x4 h3 = *(const f32x4*)(hrow + 36);
    bf16x8 a0, a1;
    #pragma unroll
    for (int j = 0; j < 4; ++j) {
        a0[j]     = (__bf16)h0[j];
        a0[j + 4] = (__bf16)h1[j];
        a1[j]     = (__bf16)h2[j];
        a1[j + 4] = (__bf16)h3[j];
    }

    // B fragment: B[k=quad*8+j][n=lane&15] = W[k][pbase+n]
    const float* wcol = W + pbase + n;
    bf16x8 b0, b1;
    #pragma unroll
    for (int j = 0; j < 8; ++j) {
        b0[j] = (__bf16)wcol[(size_t)(8 * g + j) * NP];
        b1[j] = (__bf16)wcol[(size_t)(8 * g + j + 32) * NP];
    }

    f32x4 acc = {0.f, 0.f, 0.f, 0.f};
    acc = __builtin_amdgcn_mfma_f32_16x16x32_bf16(a0, b0, acc, 0, 0, 0);
    acc = __builtin_amdgcn_mfma_f32_16x16x32_bf16(a1, b1, acc, 0, 0, 0);

    const float bb   = bias[pbase + n];
    const int b_     = bt0 / SEQ;
    const int t0     = bt0 % SEQ;
    const int h      = pbase >> 6;
    const int dbase  = pbase & 63;
    const int bh     = b_ * NH + h;

    // C layout: row = 4*quad + r, col = lane&15
    if (pi < 2) {
        __bf16* dst = (pi == 0 ? Qw : Kw) + ((size_t)bh * SEQ) * HD + dbase + n;
        #pragma unroll
        for (int r = 0; r < 4; ++r) {
            dst[(size_t)(t0 + 4 * g + r) * HD] = (__bf16)(acc[r] + bb);
        }
    } else {
        __bf16* dst = Vtw + ((size_t)bh * HD + dbase + n) * SEQ;
        #pragma unroll
        for (int r = 0; r < 4; ++r) {
            dst[t0 + 4 * g + r] = (__bf16)(acc[r] + bb);
        }
    }
}

// ---------------------------------------------------------------------------
// Kernel 2: flash attention. Block = 4 waves = one (b,h,64 q-rows) tile;
// wave owns 16 q-rows. K-loop step 32. S via 4 MFMAs, online softmax fp32,
// P C-layout -> A-layout via per-wave LDS tile, PV via 4 MFMAs (V^T input).
// ---------------------------------------------------------------------------
__global__ __launch_bounds__(256) void flash_attn_kernel(
    const __bf16* __restrict__ Qw, const __bf16* __restrict__ Kw,
    const __bf16* __restrict__ Vtw, const float* __restrict__ amask,
    float* __restrict__ out)
{
    __shared__ __align__(16) unsigned short plds[4][16][32];

    const int lane = threadIdx.x & 63;
    const int w    = threadIdx.x >> 6;
    const int g    = lane >> 4;
    const int n    = lane & 15;

    const int bid   = blockIdx.x;
    const int bh    = bid >> 5;   // 0..47
    const int qtile = bid & 31;   // 0..31
    const int b_    = bh / NH;
    const int h     = bh % NH;
    const int q0    = qtile * 64 + w * 16;

    // Q fragments (held for the whole K loop)
    const __bf16* qptr = Qw + ((size_t)bh * SEQ + q0 + n) * HD + 8 * g;
    const bf16x8 qa0 = load_bf16x8(qptr);
    const bf16x8 qa1 = load_bf16x8(qptr + 32);

    const __bf16* Kbh = Kw  + (size_t)bh * SEQ * HD;
    const __bf16* Vbh = Vtw + (size_t)bh * HD * SEQ;
    const float* mptr = amask + (size_t)b_ * SEQ;

    f32x4 o0 = {0,0,0,0}, o1 = {0,0,0,0}, o2 = {0,0,0,0}, o3 = {0,0,0,0};
    float mx[4], ls[4];
    #pragma unroll
    for (int r = 0; r < 4; ++r) { mx[r] = -1e30f; ls[r] = 0.f; }

    for (int kb = 0; kb < SEQ; kb += 32) {
        // K B-fragments: B[k=8g+j][col=n] = K[kb + ctile*16 + n][8g+j]
        const __bf16* kp0 = Kbh + (size_t)(kb + n) * HD + 8 * g;
        bf16x8 k00 = load_bf16x8(kp0);
        bf16x8 k01 = load_bf16x8(kp0 + 32);
        bf16x8 k10 = load_bf16x8(kp0 + 16 * HD);
        bf16x8 k11 = load_bf16x8(kp0 + 16 * HD + 32);

        f32x4 s0 = {0,0,0,0}, s1 = {0,0,0,0};
        s0 = __builtin_amdgcn_mfma_f32_16x16x32_bf16(qa0, k00, s0, 0, 0, 0);
        s0 = __builtin_amdgcn_mfma_f32_16x16x32_bf16(qa1, k01, s0, 0, 0, 0);
        s1 = __builtin_amdgcn_mfma_f32_16x16x32_bf16(qa0, k10, s1, 0, 0, 0);
        s1 = __builtin_amdgcn_mfma_f32_16x16x32_bf16(qa1, k11, s1, 0, 0, 0);

        const float mt0 = (1.0f - mptr[kb + n])      * -10000.0f;
        const float mt1 = (1.0f - mptr[kb + 16 + n]) * -10000.0f;

        // online softmax; row r lives on the 16 lanes of this quad-group
        float alpha[4], p0[4], p1[4];
        #pragma unroll
        for (int r = 0; r < 4; ++r) {
            float v0 = s0[r] * ATT_SCALE + mt0;
            float v1 = s1[r] * ATT_SCALE + mt1;
            float m2 = fmaxf(v0, v1);
            m2 = fmaxf(m2, __shfl_xor(m2, 1));
            m2 = fmaxf(m2, __shfl_xor(m2, 2));
            m2 = fmaxf(m2, __shfl_xor(m2, 4));
            m2 = fmaxf(m2, __shfl_xor(m2, 8));
            float mnew = fmaxf(mx[r], m2);
            float al   = __expf(mx[r] - mnew);
            mx[r]      = mnew;
            alpha[r]   = al;
            float e0 = __expf(v0 - mnew);
            float e1 = __expf(v1 - mnew);
            p0[r] = e0; p1[r] = e1;
            float rs = e0 + e1;
            rs += __shfl_xor(rs, 1);
            rs += __shfl_xor(rs, 2);
            rs += __shfl_xor(rs, 4);
            rs += __shfl_xor(rs, 8);
            ls[r] = ls[r] * al + rs;
        }
        #pragma unroll
        for (int r = 0; r < 4; ++r) {
            o0[r] *= alpha[r]; o1[r] *= alpha[r];
            o2[r] *= alpha[r]; o3[r] *= alpha[r];
        }

        // P: C-layout -> A-layout through per-wave LDS tile (16 q x 32 k)
        #pragma unroll
        for (int r = 0; r < 4; ++r) {
            plds[w][4 * g + r][n]      = __builtin_bit_cast(unsigned short, (__bf16)p0[r]);
            plds[w][4 * g + r][16 + n] = __builtin_bit_cast(unsigned short, (__bf16)p1[r]);
        }
        const bf16x8 pa = *reinterpret_cast<const bf16x8*>(&plds[w][n][8 * g]);

        // V B-fragments from V^T: B[k=8g+j][d=n] = Vt[dt*16+n][kb+8g+j]
        const __bf16* vp = Vbh + (size_t)n * SEQ + kb + 8 * g;
        o0 = __builtin_amdgcn_mfma_f32_16x16x32_bf16(pa, load_bf16x8(vp),            o0, 0, 0, 0);
        o1 = __builtin_amdgcn_mfma_f32_16x16x32_bf16(pa, load_bf16x8(vp + 16 * SEQ), o1, 0, 0, 0);
        o2 = __builtin_amdgcn_mfma_f32_16x16x32_bf16(pa, load_bf16x8(vp + 32 * SEQ), o2, 0, 0, 0);
        o3 = __builtin_amdgcn_mfma_f32_16x16x32_bf16(pa, load_bf16x8(vp + 48 * SEQ), o3, 0, 0, 0);
    }

    // epilogue: out[b][t][h*64+d], t = q0 + 4g + r, d = dt*16 + n
    float* obase = out + ((size_t)(b_ * SEQ + q0)) * NP + h * HD;
    #pragma unroll
    for (int r = 0; r < 4; ++r) {
        const float inv = 1.0f / ls[r];
        float* dst = obase + (size_t)(4 * g + r) * NP;
        dst[n]      = o0[r] * inv;
        dst[16 + n] = o1[r] * inv;
        dst[32 + n] = o2[r] * inv;
        dst[48 + n] = o3[r] * inv;
    }
}

extern "C" void kernel_launch(void* const* d_in, const int* in_sizes, int n_in,
                              void* d_out, int out_size, void* d_ws, size_t ws_size,
                              hipStream_t stream) {
    const float* hidden = (const float*)d_in[0];
    const float* amask  = (const float*)d_in[1];
    const float* Wq     = (const float*)d_in[2];
    const float* bq     = (const float*)d_in[3];
    const float* Wk     = (const float*)d_in[4];
    const float* bk     = (const float*)d_in[5];
    const float* Wv     = (const float*)d_in[6];
    const float* bv     = (const float*)d_in[7];
    float* out = (float*)d_out;

    const size_t elems = (size_t)NB * NH * SEQ * HD; // 6,291,456
    __bf16* Qw  = (__bf16*)d_ws;
    __bf16* Kw  = Qw + elems;
    __bf16* Vtw = Kw + elems;

    // Kernel 1: 128 bt-tiles x 48 p-tiles x 3 projections, 4 waves/block
    qkv_proj_kernel<<<dim3(128, 48, 3), 256, 0, stream>>>(
        hidden, Wq, bq, Wk, bk, Wv, bv, Qw, Kw, Vtw);

    // Kernel 2: 48 (b,h) x 32 q-tiles
    flash_attn_kernel<<<dim3(48 * 32), 256, 0, stream>>>(
        Qw, Kw, Vtw, amask, out);
}

// Round 2
// 435.298 us; speedup vs baseline: 1.0705x; 1.0705x over previous
//
#include <hip/hip_runtime.h>
#include <hip/hip_bf16.h>

#define NH 12
#define HD 64
#define NB 4
#define SEQ 2048
#define NP 768

typedef __bf16 bf16x8 __attribute__((ext_vector_type(8)));
typedef float f32x4 __attribute__((ext_vector_type(4)));

static __device__ __forceinline__ bf16x8 load_bf16x8(const __bf16* p) {
    return *reinterpret_cast<const bf16x8*>(p);
}

// ---------------------------------------------------------------------------
// Kernel 1 v3: QKV projection, no LDS. Block = 4 waves; wave owns 64 rows
// (4 A-frag pairs held in registers) and loops 12 p-tiles, so the strided
// W-fragment loads are amortized over 4x more output rows than v1.
// Q is pre-scaled by 0.125 (exact in bf16) so flash softmax skips the mult.
// Q,K -> (B*H, T, 64) bf16; V -> transposed (B*H, 64, T) bf16.
// grid.x = 3 proj * 4 p-chunks * 32 row-blocks = 384
// ---------------------------------------------------------------------------
__global__ __launch_bounds__(256) void qkv_proj_kernel(
    const float* __restrict__ hidden,
    const float* __restrict__ Wq, const float* __restrict__ bq,
    const float* __restrict__ Wk, const float* __restrict__ bk,
    const float* __restrict__ Wv, const float* __restrict__ bv,
    __bf16* __restrict__ Qw, __bf16* __restrict__ Kw, __bf16* __restrict__ Vtw)
{
    const int lane = threadIdx.x & 63;
    const int w    = threadIdx.x >> 6;
    const int g    = lane >> 4;
    const int n    = lane & 15;

    int bid = blockIdx.x;
    const int pi     = bid >> 7;        // 0..2
    bid &= 127;
    const int pchunk = bid & 3;         // 0..3 (12 p-tiles each)
    const int rblk   = bid >> 2;        // 0..31 (256 rows each)

    const float* W;
    const float* bias;
    if (pi == 0)      { W = Wq; bias = bq; }
    else if (pi == 1) { W = Wk; bias = bk; }
    else              { W = Wv; bias = bv; }
    const float qs = (pi == 0) ? 0.125f : 1.0f;

    const int row0 = rblk * 256 + w * 64;   // wave's 64 rows
    const int b_   = row0 >> 11;            // batch (blocks never straddle)

    // A fragments for 4 row-tiles of 16, pre-scaled for Q
    bf16x8 a0[4], a1[4];
    #pragma unroll
    for (int rt = 0; rt < 4; ++rt) {
        const float* hrow = hidden + (size_t)(row0 + 16 * rt + n) * HD + 8 * g;
        f32x4 h0 = *(const f32x4*)(hrow);
        f32x4 h1 = *(const f32x4*)(hrow + 4);
        f32x4 h2 = *(const f32x4*)(hrow + 32);
        f32x4 h3 = *(const f32x4*)(hrow + 36);
        #pragma unroll
        for (int j = 0; j < 4; ++j) {
            a0[rt][j]     = (__bf16)(h0[j] * qs);
            a0[rt][j + 4] = (__bf16)(h1[j] * qs);
            a1[rt][j]     = (__bf16)(h2[j] * qs);
            a1[rt][j + 4] = (__bf16)(h3[j] * qs);
        }
    }

    for (int pt = pchunk * 12; pt < pchunk * 12 + 12; ++pt) {
        const int pbase = pt * 16;
        // B fragment: B[k=8g+j][n] = W[k][pbase+n]
        const float* wcol = W + pbase + n;
        bf16x8 b0, b1;
        #pragma unroll
        for (int j = 0; j < 8; ++j) {
            b0[j] = (__bf16)wcol[(size_t)(8 * g + j) * NP];
            b1[j] = (__bf16)wcol[(size_t)(8 * g + j + 32) * NP];
        }
        const float bb = bias[pbase + n] * qs;

        const int h     = pbase >> 6;
        const int dbase = pbase & 63;
        const int bh    = b_ * NH + h;

        #pragma unroll
        for (int rt = 0; rt < 4; ++rt) {
            f32x4 acc = {0.f, 0.f, 0.f, 0.f};
            acc = __builtin_amdgcn_mfma_f32_16x16x32_bf16(a0[rt], b0, acc, 0, 0, 0);
            acc = __builtin_amdgcn_mfma_f32_16x16x32_bf16(a1[rt], b1, acc, 0, 0, 0);
            const int t0 = (row0 + 16 * rt) & (SEQ - 1);
            if (pi < 2) {
                __bf16* dst = (pi == 0 ? Qw : Kw) + ((size_t)bh * SEQ) * HD + dbase + n;
                #pragma unroll
                for (int r = 0; r < 4; ++r)
                    dst[(size_t)(t0 + 4 * g + r) * HD] = (__bf16)(acc[r] + bb);
            } else {
                __bf16* dst = Vtw + ((size_t)bh * HD + dbase + n) * SEQ;
                #pragma unroll
                for (int r = 0; r < 4; ++r)
                    dst[t0 + 4 * g + r] = (__bf16)(acc[r] + bb);
            }
        }
    }
}

// ---------------------------------------------------------------------------
// Kernel 2 v3: flash attention, K-step 64.
// Per iter: 8 S-MFMAs, online softmax (per-lane partial row-sums, single
// cross-lane max reduce), padded LDS P-transpose (stride 72 shorts: 2-way
// bank aliasing = free), 8 PV MFMAs. Q arrives pre-scaled by 0.125.
// ---------------------------------------------------------------------------
__global__ __launch_bounds__(256) void flash_attn_kernel(
    const __bf16* __restrict__ Qw, const __bf16* __restrict__ Kw,
    const __bf16* __restrict__ Vtw, const float* __restrict__ amask,
    float* __restrict__ out)
{
    __shared__ __align__(16) unsigned short plds[4][16][72];

    const int lane = threadIdx.x & 63;
    const int w    = threadIdx.x >> 6;
    const int g    = lane >> 4;
    const int n    = lane & 15;

    const int bid   = blockIdx.x;
    const int bh    = bid >> 5;
    const int qtile = bid & 31;
    const int b_    = bh / NH;
    const int q0    = qtile * 64 + w * 16;

    const __bf16* qptr = Qw + ((size_t)bh * SEQ + q0 + n) * HD + 8 * g;
    const bf16x8 qa0 = load_bf16x8(qptr);
    const bf16x8 qa1 = load_bf16x8(qptr + 32);

    const __bf16* Kbh = Kw  + (size_t)bh * SEQ * HD;
    const __bf16* Vbh = Vtw + (size_t)bh * HD * SEQ;
    const float* mptr = amask + (size_t)b_ * SEQ;

    f32x4 o0 = {0,0,0,0}, o1 = {0,0,0,0}, o2 = {0,0,0,0}, o3 = {0,0,0,0};
    float mx[4], lsl[4];
    #pragma unroll
    for (int r = 0; r < 4; ++r) { mx[r] = -1e30f; lsl[r] = 0.f; }

    for (int kb = 0; kb < SEQ; kb += 64) {
        // V B-fragments (longest use-distance: load first)
        const __bf16* vp = Vbh + (size_t)n * SEQ + kb + 8 * g;
        bf16x8 vf[4][2];
        #pragma unroll
        for (int dt = 0; dt < 4; ++dt) {
            vf[dt][0] = load_bf16x8(vp + (size_t)dt * 16 * SEQ);
            vf[dt][1] = load_bf16x8(vp + (size_t)dt * 16 * SEQ + 32);
        }
        // K B-fragments: 4 column tiles of 16 keys
        const __bf16* kp = Kbh + (size_t)(kb + n) * HD + 8 * g;
        bf16x8 kf0[4], kf1[4];
        #pragma unroll
        for (int c = 0; c < 4; ++c) {
            kf0[c] = load_bf16x8(kp + (size_t)c * 16 * HD);
            kf1[c] = load_bf16x8(kp + (size_t)c * 16 * HD + 32);
        }
        float mt[4];
        #pragma unroll
        for (int c = 0; c < 4; ++c)
            mt[c] = (1.0f - mptr[kb + 16 * c + n]) * -10000.0f;

        // S = Q K^T (Q pre-scaled)
        f32x4 s[4];
        #pragma unroll
        for (int c = 0; c < 4; ++c) {
            f32x4 z = {0,0,0,0};
            z = __builtin_amdgcn_mfma_f32_16x16x32_bf16(qa0, kf0[c], z, 0, 0, 0);
            z = __builtin_amdgcn_mfma_f32_16x16x32_bf16(qa1, kf1[c], z, 0, 0, 0);
            s[c] = z;
        }

        // online softmax; row r lives on this quad's 16 lanes
        float vv[4][4];
        #pragma unroll
        for (int c = 0; c < 4; ++c)
            #pragma unroll
            for (int r = 0; r < 4; ++r)
                vv[c][r] = s[c][r] + mt[c];

        float al[4];
        #pragma unroll
        for (int r = 0; r < 4; ++r) {
            float m2 = fmaxf(fmaxf(vv[0][r], vv[1][r]), fmaxf(vv[2][r], vv[3][r]));
            m2 = fmaxf(m2, __shfl_xor(m2, 1));
            m2 = fmaxf(m2, __shfl_xor(m2, 2));
            m2 = fmaxf(m2, __shfl_xor(m2, 4));
            m2 = fmaxf(m2, __shfl_xor(m2, 8));
            const float mnew = fmaxf(mx[r], m2);
            al[r] = __expf(mx[r] - mnew);
            mx[r] = mnew;
            float e0 = __expf(vv[0][r] - mnew);
            float e1 = __expf(vv[1][r] - mnew);
            float e2 = __expf(vv[2][r] - mnew);
            float e3 = __expf(vv[3][r] - mnew);
            vv[0][r] = e0; vv[1][r] = e1; vv[2][r] = e2; vv[3][r] = e3;
            // per-lane partial sum: alpha is quad-uniform, reduce at end
            lsl[r] = lsl[r] * al[r] + ((e0 + e1) + (e2 + e3));
        }
        #pragma unroll
        for (int r = 0; r < 4; ++r) {
            o0[r] *= al[r]; o1[r] *= al[r];
            o2[r] *= al[r]; o3[r] *= al[r];
        }

        // P: C-layout -> A-layout via padded per-wave LDS tile (16 x 64)
        #pragma unroll
        for (int c = 0; c < 4; ++c)
            #pragma unroll
            for (int r = 0; r < 4; ++r)
                plds[w][4 * g + r][16 * c + n] =
                    __builtin_bit_cast(unsigned short, (__bf16)vv[c][r]);

        const bf16x8 pa0 = *reinterpret_cast<const bf16x8*>(&plds[w][n][8 * g]);
        const bf16x8 pa1 = *reinterpret_cast<const bf16x8*>(&plds[w][n][32 + 8 * g]);

        o0 = __builtin_amdgcn_mfma_f32_16x16x32_bf16(pa0, vf[0][0], o0, 0, 0, 0);
        o0 = __builtin_amdgcn_mfma_f32_16x16x32_bf16(pa1, vf[0][1], o0, 0, 0, 0);
        o1 = __builtin_amdgcn_mfma_f32_16x16x32_bf16(pa0, vf[1][0], o1, 0, 0, 0);
        o1 = __builtin_amdgcn_mfma_f32_16x16x32_bf16(pa1, vf[1][1], o1, 0, 0, 0);
        o2 = __builtin_amdgcn_mfma_f32_16x16x32_bf16(pa0, vf[2][0], o2, 0, 0, 0);
        o2 = __builtin_amdgcn_mfma_f32_16x16x32_bf16(pa1, vf[2][1], o2, 0, 0, 0);
        o3 = __builtin_amdgcn_mfma_f32_16x16x32_bf16(pa0, vf[3][0], o3, 0, 0, 0);
        o3 = __builtin_amdgcn_mfma_f32_16x16x32_bf16(pa1, vf[3][1], o3, 0, 0, 0);
    }

    // final cross-lane sum of the per-lane partials (once)
    float inv[4];
    #pragma unroll
    for (int r = 0; r < 4; ++r) {
        float rs = lsl[r];
        rs += __shfl_xor(rs, 1);
        rs += __shfl_xor(rs, 2);
        rs += __shfl_xor(rs, 4);
        rs += __shfl_xor(rs, 8);
        inv[r] = 1.0f / rs;
    }

    const int h = bh % NH;
    float* obase = out + ((size_t)(b_ * SEQ + q0)) * NP + h * HD;
    #pragma unroll
    for (int r = 0; r < 4; ++r) {
        float* dst = obase + (size_t)(4 * g + r) * NP;
        dst[n]      = o0[r] * inv[r];
        dst[16 + n] = o1[r] * inv[r];
        dst[32 + n] = o2[r] * inv[r];
        dst[48 + n] = o3[r] * inv[r];
    }
}

extern "C" void kernel_launch(void* const* d_in, const int* in_sizes, int n_in,
                              void* d_out, int out_size, void* d_ws, size_t ws_size,
                              hipStream_t stream) {
    const float* hidden = (const float*)d_in[0];
    const float* amask  = (const float*)d_in[1];
    const float* Wq     = (const float*)d_in[2];
    const float* bq     = (const float*)d_in[3];
    const float* Wk     = (const float*)d_in[4];
    const float* bk     = (const float*)d_in[5];
    const float* Wv     = (const float*)d_in[6];
    const float* bv     = (const float*)d_in[7];
    float* out = (float*)d_out;

    const size_t elems = (size_t)NB * NH * SEQ * HD; // 6,291,456
    __bf16* Qw  = (__bf16*)d_ws;
    __bf16* Kw  = Qw + elems;
    __bf16* Vtw = Kw + elems;

    qkv_proj_kernel<<<dim3(384), 256, 0, stream>>>(
        hidden, Wq, bq, Wk, bk, Wv, bv, Qw, Kw, Vtw);

    flash_attn_kernel<<<dim3(48 * 32), 256, 0, stream>>>(
        Qw, Kw, Vtw, amask, out);
}